// Round 4
// baseline (1638.694 us; speedup 1.0000x reference)
//
#include <hip/hip_runtime.h>

typedef unsigned short u16;
typedef unsigned int u32;
typedef unsigned long long u64;
typedef short bf16x8 __attribute__((ext_vector_type(8)));
typedef float f32x4 __attribute__((ext_vector_type(4)));

__device__ __forceinline__ float b2f(u16 u) {
    return __uint_as_float(((u32)u) << 16);
}
__device__ __forceinline__ u16 f2b(float f) {  // RNE
    u32 u = __float_as_uint(f);
    u32 r = u + 0x7fffu + ((u >> 16) & 1u);
    return (u16)(r >> 16);
}
__device__ __forceinline__ f32x4 mfma16(bf16x8 a, bf16x8 b, f32x4 c) {
    return __builtin_amdgcn_mfma_f32_16x16x32_bf16(a, b, c, 0, 0, 0);
}

// ---------------------------------------------------------------------------
// Weight transpose/pad/split: src f32 [R][C] row-major. dst: hi plane [NP][KP]
// bf16 then lo plane [NP][KP] bf16 (residual). Zero-pad k>=R or n>=C.
// ---------------------------------------------------------------------------
template<int NP, int KP, int R, int C>
__device__ __forceinline__ bool seg(int t, int base, const float* src, u16* dst) {
    int r = t - base;
    if (r < 0) return true;
    if (r >= NP * KP) return false;
    int n = r / KP, k = r - n * KP;
    float v = (k < R && n < C) ? src[k * C + n] : 0.f;
    u16 hi = f2b(v);
    dst[r] = hi;
    dst[NP * KP + r] = f2b(v - b2f(hi));
    return true;
}

__global__ __launch_bounds__(256) void prep_weights(
    const float* w1a, const float* w1b, const float* w2a, const float* w2b,
    const float* w3a, const float* w3b, const float* wf1, const float* wf2,
    const float* wf3,
    u16* t1a, u16* t1b, u16* t2a, u16* t2b, u16* t3a, u16* t3b,
    u16* tf1, u16* tf2, u16* tf3)
{
    int t = blockIdx.x * 256 + threadIdx.x;
    if (seg< 64,  32,   6,  64>(t,      0, w1a, t1a)) return;
    if (seg< 64,  64,  64,  64>(t,   2048, w1b, t1b)) return;
    if (seg< 64, 128, 128,  64>(t,   6144, w2a, t2a)) return;
    if (seg<128,  64,  64, 128>(t,  14336, w2b, t2b)) return;
    if (seg<128, 256, 256, 128>(t,  22528, w3a, t3a)) return;
    if (seg<512, 128, 128, 512>(t,  55296, w3b, t3b)) return;
    if (seg<512, 704, 704, 512>(t, 120832, wf1, tf1)) return;
    if (seg<256, 512, 512, 256>(t, 481280, wf2, tf2)) return;
    if (seg< 16, 256, 256,  12>(t, 612352, wf3, tf3)) return;
}

// ---------------------------------------------------------------------------
// kNN: one WG (256 thr) per (b,n) row, f32, exact numpy op order (no FMA
// contraction). 32x argmin, tie-break lowest index (matches lax.top_k).
// ---------------------------------------------------------------------------
__global__ __launch_bounds__(256) void knn_kernel(const float* __restrict__ pos,
                                                  int* __restrict__ idxout)
{
    int p = blockIdx.x;
    int b = p >> 11, n = p & 2047;
    int tid = threadIdx.x;
    __shared__ u64 red[4];
    __shared__ int sel_s;

    const float* pb = pos + (size_t)b * 2048 * 3;
    float pn0 = pb[n * 3 + 0], pn1 = pb[n * 3 + 1], pn2 = pb[n * 3 + 2];
    float sqn = __fadd_rn(__fadd_rn(__fmul_rn(pn0, pn0), __fmul_rn(pn1, pn1)),
                          __fmul_rn(pn2, pn2));
    u64 keys[8];
#pragma unroll
    for (int j = 0; j < 8; ++j) {
        int m = tid + j * 256;
        float q0 = pb[m * 3 + 0], q1 = pb[m * 3 + 1], q2 = pb[m * 3 + 2];
        float sqm = __fadd_rn(__fadd_rn(__fmul_rn(q0, q0), __fmul_rn(q1, q1)),
                              __fmul_rn(q2, q2));
        float dot = __fadd_rn(__fadd_rn(__fmul_rn(pn0, q0), __fmul_rn(pn1, q1)),
                              __fmul_rn(pn2, q2));
        float d2 = __fadd_rn(__fsub_rn(sqn, __fmul_rn(2.0f, dot)), sqm);
        u32 u = __float_as_uint(d2);
        u = (u & 0x80000000u) ? ~u : (u | 0x80000000u);  // orderable
        keys[j] = (((u64)u) << 32) | (u32)m;
    }
    int lane = tid & 63, w = tid >> 6;
    for (int it = 0; it < 32; ++it) {
        u64 k = keys[0];
#pragma unroll
        for (int j = 1; j < 8; ++j) { u64 o = keys[j]; k = (o < k) ? o : k; }
        u32 hi = (u32)(k >> 32), lo = (u32)k;
#pragma unroll
        for (int off = 32; off; off >>= 1) {
            u32 ohi = __shfl_xor(hi, off);
            u32 olo = __shfl_xor(lo, off);
            if (ohi < hi || (ohi == hi && olo < lo)) { hi = ohi; lo = olo; }
        }
        if (lane == 0) red[w] = (((u64)hi) << 32) | lo;
        __syncthreads();
        if (tid == 0) {
            u64 a = (red[0] < red[1]) ? red[0] : red[1];
            u64 c = (red[2] < red[3]) ? red[2] : red[3];
            u64 kk = (a < c) ? a : c;
            sel_s = (int)(kk & 0xffffffffu);
            idxout[(size_t)p * 32 + it] = (int)(kk & 0x7ff);
        }
        __syncthreads();
        int sel = sel_s;
        if ((sel & 255) == tid) keys[(sel >> 8) & 7] = ~0ull;
    }
}

// ---------------------------------------------------------------------------
// Fused edge block (split-bf16, ~f32 accurate): one WG (4 waves) per point.
// feat[32][KD] = [x_c, nb-x_c, 0pad]; h = lrelu(feat@Wa+ba);
// out = lrelu(max_k(h@Wb)+bb). 3-term MFMA: AH*WH + AH*WL + AL*WH.
// A-frag: A[m=lane&15][k=q*8+j]; B-frag: B[k=q*8+j][n=lane&15];
// C/D: col=lane&15, row=q*4+reg.
// ---------------------------------------------------------------------------
template<int KD, int CIN, int CMID, int COUT>
__global__ __launch_bounds__(256) void edge_block(
    const float* __restrict__ xin, const int* __restrict__ idx,
    const u16* __restrict__ waT, const float* __restrict__ ba,
    const u16* __restrict__ wbT, const float* __restrict__ bb,
    float* __restrict__ out)
{
    constexpr int SF = KD + 8;
    constexpr int SH = CMID + 8;
    constexpr int WA_SZ = CMID * KD;    // hi-plane size of Wa
    constexpr int WB_SZ = COUT * CMID;  // hi-plane size of Wb
    __shared__ __align__(16) u16 featH[32 * SF];
    __shared__ __align__(16) u16 featL[32 * SF];
    __shared__ __align__(16) u16 hbufH[32 * SH];
    __shared__ __align__(16) u16 hbufL[32 * SH];
    __shared__ int nbr[32];

    int p = blockIdx.x;
    int b = p >> 11;
    int tid = threadIdx.x, lane = tid & 63, w = tid >> 6;
    int ln = lane & 15, q = lane >> 4;

    if (tid < 32) nbr[tid] = (b << 11) + (idx[(size_t)p * 32 + tid] & 2047);
    __syncthreads();

    // build edge features (f32 math, then hi/lo split)
    {
        int c = tid % KD;
        int cc = (c < CIN) ? c : ((c < 2 * CIN) ? c - CIN : -1);
        float xcv = (cc >= 0) ? xin[(size_t)p * CIN + cc] : 0.f;
        for (int j = tid / KD; j < 32; j += 256 / KD) {
            float v = 0.f;
            if (c < CIN) v = xcv;
            else if (c < 2 * CIN) v = xin[(size_t)nbr[j] * CIN + cc] - xcv;
            u16 hi = f2b(v);
            featH[j * SF + c] = hi;
            featL[j * SF + c] = f2b(v - b2f(hi));
        }
    }
    __syncthreads();

    // matmul-a: [32 x KD] @ [KD x CMID]
    constexpr int NTA = CMID / 64;
    f32x4 accA[2][NTA] = {};
    const int wbaseA = w * (CMID / 4);
#pragma unroll
    for (int ks = 0; ks < KD / 32; ++ks) {
        bf16x8 a0h = *(const bf16x8*)&featH[(ln) * SF + ks * 32 + q * 8];
        bf16x8 a1h = *(const bf16x8*)&featH[(16 + ln) * SF + ks * 32 + q * 8];
        bf16x8 a0l = *(const bf16x8*)&featL[(ln) * SF + ks * 32 + q * 8];
        bf16x8 a1l = *(const bf16x8*)&featL[(16 + ln) * SF + ks * 32 + q * 8];
#pragma unroll
        for (int nt = 0; nt < NTA; ++nt) {
            size_t wi = (size_t)(wbaseA + nt * 16 + ln) * KD + ks * 32 + q * 8;
            bf16x8 bh = *(const bf16x8*)&waT[wi];
            bf16x8 bl = *(const bf16x8*)&waT[WA_SZ + wi];
            accA[0][nt] = mfma16(a0h, bh, accA[0][nt]);
            accA[0][nt] = mfma16(a0h, bl, accA[0][nt]);
            accA[0][nt] = mfma16(a0l, bh, accA[0][nt]);
            accA[1][nt] = mfma16(a1h, bh, accA[1][nt]);
            accA[1][nt] = mfma16(a1h, bl, accA[1][nt]);
            accA[1][nt] = mfma16(a1l, bh, accA[1][nt]);
        }
    }
    // bias + lrelu -> h (hi/lo split)
#pragma unroll
    for (int nt = 0; nt < NTA; ++nt) {
        int col = wbaseA + nt * 16 + ln;
        float bias = ba[col];
#pragma unroll
        for (int mt = 0; mt < 2; ++mt)
#pragma unroll
            for (int r = 0; r < 4; ++r) {
                float v = accA[mt][nt][r] + bias;
                v = v >= 0.f ? v : 0.2f * v;
                u16 hi = f2b(v);
                int a = (mt * 16 + q * 4 + r) * SH + col;
                hbufH[a] = hi;
                hbufL[a] = f2b(v - b2f(hi));
            }
    }
    __syncthreads();

    // matmul-b: [32 x CMID] @ [CMID x COUT]
    constexpr int NTB = COUT / 64;
    f32x4 accB[2][NTB] = {};
    const int wbaseB = w * (COUT / 4);
#pragma unroll
    for (int ks = 0; ks < CMID / 32; ++ks) {
        bf16x8 a0h = *(const bf16x8*)&hbufH[(ln) * SH + ks * 32 + q * 8];
        bf16x8 a1h = *(const bf16x8*)&hbufH[(16 + ln) * SH + ks * 32 + q * 8];
        bf16x8 a0l = *(const bf16x8*)&hbufL[(ln) * SH + ks * 32 + q * 8];
        bf16x8 a1l = *(const bf16x8*)&hbufL[(16 + ln) * SH + ks * 32 + q * 8];
#pragma unroll
        for (int nt = 0; nt < NTB; ++nt) {
            size_t wi = (size_t)(wbaseB + nt * 16 + ln) * CMID + ks * 32 + q * 8;
            bf16x8 bh = *(const bf16x8*)&wbT[wi];
            bf16x8 bl = *(const bf16x8*)&wbT[WB_SZ + wi];
            accB[0][nt] = mfma16(a0h, bh, accB[0][nt]);
            accB[0][nt] = mfma16(a0h, bl, accB[0][nt]);
            accB[0][nt] = mfma16(a0l, bh, accB[0][nt]);
            accB[1][nt] = mfma16(a1h, bh, accB[1][nt]);
            accB[1][nt] = mfma16(a1h, bl, accB[1][nt]);
            accB[1][nt] = mfma16(a1l, bh, accB[1][nt]);
        }
    }
    // max over 32 neighbor rows, then bias+lrelu (lrelu monotone, bias/col)
#pragma unroll
    for (int nt = 0; nt < NTB; ++nt) {
        int col = wbaseB + nt * 16 + ln;
        float m = accB[0][nt][0];
#pragma unroll
        for (int r = 1; r < 4; ++r) m = fmaxf(m, accB[0][nt][r]);
#pragma unroll
        for (int r = 0; r < 4; ++r) m = fmaxf(m, accB[1][nt][r]);
        m = fmaxf(m, __shfl_xor(m, 16));
        m = fmaxf(m, __shfl_xor(m, 32));
        if (q == 0) {
            float v = m + bb[col];
            v = v >= 0.f ? v : 0.2f * v;
            out[(size_t)p * COUT + col] = v;
        }
    }
}

// ---------------------------------------------------------------------------
// Head GEMM 1: fused concat [x1|x2|x3] (704) -> 512, lrelu. 32 rows / WG.
// K tiled 2x352 to fit LDS. out may alias x3 in-place (all writes after all
// reads of this block's rows; no cross-block row sharing).
// ---------------------------------------------------------------------------
__global__ __launch_bounds__(256) void head1(
    const float* __restrict__ x1, const float* __restrict__ x2,
    const float* __restrict__ x3,
    const u16* __restrict__ wT, const float* __restrict__ bias,
    float* __restrict__ out)
{
    constexpr int KD = 704, KT = 352, SA = 360, COUT = 512;
    constexpr int W_SZ = 512 * 704;
    __shared__ __align__(16) u16 AsH[32 * SA];
    __shared__ __align__(16) u16 AsL[32 * SA];
    int row0 = blockIdx.x * 32;
    int tid = threadIdx.x, lane = tid & 63, w = tid >> 6, ln = lane & 15, q = lane >> 4;

    f32x4 acc[2][8] = {};
    const int wbase = w * 128;

    for (int ph = 0; ph < 2; ++ph) {
        if (ph) __syncthreads();
        for (int e = tid; e < 32 * KT; e += 256) {
            int r = e / KT, c = e - r * KT + ph * KT;
            int g = row0 + r;
            float v;
            if (c < 64)       v = x1[(size_t)g * 64 + c];
            else if (c < 192) v = x2[(size_t)g * 128 + (c - 64)];
            else              v = x3[(size_t)g * 512 + (c - 192)];
            u16 hi = f2b(v);
            int a = r * SA + (e - r * KT);
            AsH[a] = hi;
            AsL[a] = f2b(v - b2f(hi));
        }
        __syncthreads();
        for (int ks = 0; ks < KT / 32; ++ks) {
            bf16x8 a0h = *(const bf16x8*)&AsH[(ln) * SA + ks * 32 + q * 8];
            bf16x8 a1h = *(const bf16x8*)&AsH[(16 + ln) * SA + ks * 32 + q * 8];
            bf16x8 a0l = *(const bf16x8*)&AsL[(ln) * SA + ks * 32 + q * 8];
            bf16x8 a1l = *(const bf16x8*)&AsL[(16 + ln) * SA + ks * 32 + q * 8];
#pragma unroll
            for (int nt = 0; nt < 8; ++nt) {
                size_t wi = (size_t)(wbase + nt * 16 + ln) * KD + ph * KT + ks * 32 + q * 8;
                bf16x8 bh = *(const bf16x8*)&wT[wi];
                bf16x8 bl = *(const bf16x8*)&wT[W_SZ + wi];
                acc[0][nt] = mfma16(a0h, bh, acc[0][nt]);
                acc[0][nt] = mfma16(a0h, bl, acc[0][nt]);
                acc[0][nt] = mfma16(a0l, bh, acc[0][nt]);
                acc[1][nt] = mfma16(a1h, bh, acc[1][nt]);
                acc[1][nt] = mfma16(a1h, bl, acc[1][nt]);
                acc[1][nt] = mfma16(a1l, bh, acc[1][nt]);
            }
        }
    }
#pragma unroll
    for (int nt = 0; nt < 8; ++nt) {
        int col = wbase + nt * 16 + ln;
        float bv = bias[col];
#pragma unroll
        for (int mt = 0; mt < 2; ++mt)
#pragma unroll
            for (int r = 0; r < 4; ++r) {
                float v = acc[mt][nt][r] + bv;
                v = v >= 0.f ? v : 0.2f * v;
                out[(size_t)(row0 + mt * 16 + q * 4 + r) * COUT + col] = v;
            }
    }
}

// ---------------------------------------------------------------------------
// Head GEMM generic: KD -> COUT f32 in/out, K tiled by KT, optional lrelu.
// ---------------------------------------------------------------------------
template<int KD, int KT, int COUT, bool ACT>
__global__ __launch_bounds__(256) void head_gemm(
    const float* __restrict__ A, const u16* __restrict__ wT,
    const float* __restrict__ bias, float* __restrict__ out)
{
    constexpr int SA = KT + 8;
    constexpr int W_SZ = COUT * KD;
    __shared__ __align__(16) u16 AsH[32 * SA];
    __shared__ __align__(16) u16 AsL[32 * SA];
    int row0 = blockIdx.x * 32;
    int tid = threadIdx.x, lane = tid & 63, w = tid >> 6, ln = lane & 15, q = lane >> 4;

    constexpr int NT = COUT / 64;
    f32x4 acc[2][NT] = {};
    const int wbase = w * (COUT / 4);

    for (int ph = 0; ph < KD / KT; ++ph) {
        if (ph) __syncthreads();
        for (int e = tid; e < 32 * KT; e += 256) {
            int r = e / KT, c = e - r * KT;
            float v = A[(size_t)(row0 + r) * KD + ph * KT + c];
            u16 hi = f2b(v);
            AsH[r * SA + c] = hi;
            AsL[r * SA + c] = f2b(v - b2f(hi));
        }
        __syncthreads();
        for (int ks = 0; ks < KT / 32; ++ks) {
            bf16x8 a0h = *(const bf16x8*)&AsH[(ln) * SA + ks * 32 + q * 8];
            bf16x8 a1h = *(const bf16x8*)&AsH[(16 + ln) * SA + ks * 32 + q * 8];
            bf16x8 a0l = *(const bf16x8*)&AsL[(ln) * SA + ks * 32 + q * 8];
            bf16x8 a1l = *(const bf16x8*)&AsL[(16 + ln) * SA + ks * 32 + q * 8];
#pragma unroll
            for (int nt = 0; nt < NT; ++nt) {
                size_t wi = (size_t)(wbase + nt * 16 + ln) * KD + ph * KT + ks * 32 + q * 8;
                bf16x8 bh = *(const bf16x8*)&wT[wi];
                bf16x8 bl = *(const bf16x8*)&wT[W_SZ + wi];
                acc[0][nt] = mfma16(a0h, bh, acc[0][nt]);
                acc[0][nt] = mfma16(a0h, bl, acc[0][nt]);
                acc[0][nt] = mfma16(a0l, bh, acc[0][nt]);
                acc[1][nt] = mfma16(a1h, bh, acc[1][nt]);
                acc[1][nt] = mfma16(a1h, bl, acc[1][nt]);
                acc[1][nt] = mfma16(a1l, bh, acc[1][nt]);
            }
        }
    }
#pragma unroll
    for (int nt = 0; nt < NT; ++nt) {
        int col = wbase + nt * 16 + ln;
        float bv = bias[col];
#pragma unroll
        for (int mt = 0; mt < 2; ++mt)
#pragma unroll
            for (int r = 0; r < 4; ++r) {
                float v = acc[mt][nt][r] + bv;
                if (ACT) v = v >= 0.f ? v : 0.2f * v;
                out[(size_t)(row0 + mt * 16 + q * 4 + r) * COUT + col] = v;
            }
    }
}

// ---------------------------------------------------------------------------
// Head GEMM 3: 256 -> 12 (N padded 16), f32 in/out, A from global (L2-hot),
// register hi/lo split. One wave per 32-row strip.
// ---------------------------------------------------------------------------
__global__ __launch_bounds__(256) void head_gemm3(
    const float* __restrict__ A, const u16* __restrict__ wT,
    const float* __restrict__ bias, float* __restrict__ out)
{
    constexpr int W_SZ = 16 * 256;
    int tid = threadIdx.x, lane = tid & 63, w = tid >> 6, ln = lane & 15, q = lane >> 4;
    int row0 = (blockIdx.x * 4 + w) * 32;
    f32x4 acc[2] = {};
#pragma unroll
    for (int ks = 0; ks < 8; ++ks) {
        bf16x8 aH[2], aL[2];
#pragma unroll
        for (int mt = 0; mt < 2; ++mt) {
            const float* src = &A[(size_t)(row0 + mt * 16 + ln) * 256 + ks * 32 + q * 8];
            f32x4 v0 = *(const f32x4*)src;
            f32x4 v1 = *(const f32x4*)(src + 4);
#pragma unroll
            for (int i = 0; i < 4; ++i) {
                u16 h0 = f2b(v0[i]); aH[mt][i] = h0; aL[mt][i] = f2b(v0[i] - b2f(h0));
                u16 h1 = f2b(v1[i]); aH[mt][4 + i] = h1; aL[mt][4 + i] = f2b(v1[i] - b2f(h1));
            }
        }
        size_t wi = (size_t)ln * 256 + ks * 32 + q * 8;
        bf16x8 bh = *(const bf16x8*)&wT[wi];
        bf16x8 bl = *(const bf16x8*)&wT[W_SZ + wi];
#pragma unroll
        for (int mt = 0; mt < 2; ++mt) {
            acc[mt] = mfma16(aH[mt], bh, acc[mt]);
            acc[mt] = mfma16(aH[mt], bl, acc[mt]);
            acc[mt] = mfma16(aL[mt], bh, acc[mt]);
        }
    }
    if (ln < 12) {
        float bv = bias[ln];
#pragma unroll
        for (int mt = 0; mt < 2; ++mt)
#pragma unroll
            for (int r = 0; r < 4; ++r)
                out[(size_t)(row0 + mt * 16 + q * 4 + r) * 12 + ln] = acc[mt][r] + bv;
    }
}

// ---------------------------------------------------------------------------
// Workspace (peak 52,797,440 B ~= 50.4 MB):
//   [0,          2465792)  split weights (hi+lo bf16)
//   [2465792,    4562944)  idxb              (dead after edge3)
//   [4562944,    8757248)  x1 f32            (dead after head1)
//   [8757248,   17145856)  x2 f32            (dead after head1)
//   [19243008,  52797440)  x3 f32; h1 overwrites in-place
//   h2 f32 16 MB @ 2465792..19243008 (over dead idxb/x1/x2/gap)
// ---------------------------------------------------------------------------
extern "C" void kernel_launch(void* const* d_in, const int* in_sizes, int n_in,
                              void* d_out, int out_size, void* d_ws, size_t ws_size,
                              hipStream_t stream)
{
    (void)in_sizes; (void)n_in; (void)out_size; (void)ws_size;
    const float* x   = (const float*)d_in[0];
    const float* pos = (const float*)d_in[1];
    const float* w1a = (const float*)d_in[2];  const float* b1a = (const float*)d_in[3];
    const float* w1b = (const float*)d_in[4];  const float* b1b = (const float*)d_in[5];
    const float* w2a = (const float*)d_in[6];  const float* b2a = (const float*)d_in[7];
    const float* w2b = (const float*)d_in[8];  const float* b2b = (const float*)d_in[9];
    const float* w3a = (const float*)d_in[10]; const float* b3a = (const float*)d_in[11];
    const float* w3b = (const float*)d_in[12]; const float* b3b = (const float*)d_in[13];
    const float* wf1 = (const float*)d_in[14]; const float* bf1 = (const float*)d_in[15];
    const float* wf2 = (const float*)d_in[16]; const float* bf2 = (const float*)d_in[17];
    const float* wf3 = (const float*)d_in[18]; const float* bf3 = (const float*)d_in[19];

    char* ws = (char*)d_ws;
    u16* t1a = (u16*)(ws + 0);         // 2*64*32
    u16* t1b = (u16*)(ws + 8192);      // 2*64*64
    u16* t2a = (u16*)(ws + 24576);     // 2*64*128
    u16* t2b = (u16*)(ws + 57344);     // 2*128*64
    u16* t3a = (u16*)(ws + 90112);     // 2*128*256
    u16* t3b = (u16*)(ws + 221184);    // 2*512*128
    u16* tf1 = (u16*)(ws + 483328);    // 2*512*704
    u16* tf2 = (u16*)(ws + 1925120);   // 2*256*512
    u16* tf3 = (u16*)(ws + 2449408);   // 2*16*256
    int*   idxb = (int*)(ws + 2465792);
    float* x1 = (float*)(ws + 4562944);
    float* x2 = (float*)(ws + 8757248);
    float* x3 = (float*)(ws + 19243008);
    float* h1 = x3;                    // in-place
    float* h2 = (float*)(ws + 2465792);

    prep_weights<<<2408, 256, 0, stream>>>(w1a, w1b, w2a, w2b, w3a, w3b, wf1, wf2, wf3,
                                           t1a, t1b, t2a, t2b, t3a, t3b, tf1, tf2, tf3);
    knn_kernel<<<16384, 256, 0, stream>>>(pos, idxb);
    edge_block< 32,   3,  64,  64><<<16384, 256, 0, stream>>>(x,  idxb, t1a, b1a, t1b, b1b, x1);
    edge_block<128,  64,  64, 128><<<16384, 256, 0, stream>>>(x1, idxb, t2a, b2a, t2b, b2b, x2);
    edge_block<256, 128, 128, 512><<<16384, 256, 0, stream>>>(x2, idxb, t3a, b3a, t3b, b3b, x3);
    head1<<<512, 256, 0, stream>>>(x1, x2, x3, tf1, bf1, h1);
    head_gemm<512, 256, 256, true><<<512, 256, 0, stream>>>(h1, tf2, bf2, h2);
    head_gemm3<<<128, 256, 0, stream>>>(h2, tf3, bf3, (float*)d_out);
}

// Round 5
// 958.642 us; speedup vs baseline: 1.7094x; 1.7094x over previous
//
#include <hip/hip_runtime.h>

typedef unsigned short u16;
typedef unsigned int u32;
typedef unsigned long long u64;
typedef short bf16x8 __attribute__((ext_vector_type(8)));
typedef float f32x4 __attribute__((ext_vector_type(4)));

__device__ __forceinline__ float b2f(u16 u) {
    return __uint_as_float(((u32)u) << 16);
}
__device__ __forceinline__ u16 f2b(float f) {  // RNE
    u32 u = __float_as_uint(f);
    u32 r = u + 0x7fffu + ((u >> 16) & 1u);
    return (u16)(r >> 16);
}
__device__ __forceinline__ f32x4 mfma16(bf16x8 a, bf16x8 b, f32x4 c) {
    return __builtin_amdgcn_mfma_f32_16x16x32_bf16(a, b, c, 0, 0, 0);
}

// ---------------------------------------------------------------------------
// prep: weight transforms. All weights stored transposed W^T[n][k] as split
// bf16 (hi plane then lo plane).
// seg: plain transpose/pad/split of src [R][C] -> [NP][KP].
// ---------------------------------------------------------------------------
template<int NP, int KP, int R, int C>
__device__ __forceinline__ bool seg(int t, int base, const float* src, u16* dst) {
    int r = t - base;
    if (r < 0) return true;
    constexpr int RNG = NP * KP;
    if (r >= RNG) return false;
    int n = r / KP, k = r - n * KP;
    float v = (k < R && n < C) ? src[k * C + n] : 0.f;
    u16 hi = f2b(v);
    dst[r] = hi;
    dst[RNG + r] = f2b(v - b2f(hi));
    return true;
}
// seg_uv: builds stacked [(Wa1-Wa2)^T ; Wa2^T] of shape [2*CMID][KP] from
// wa [2*CIN][CMID] row-major. Zero-pad k>=CIN.
template<int CMID, int CIN, int KP>
__device__ __forceinline__ bool seg_uv(int t, int base, const float* wa, u16* dst) {
    int r = t - base;
    if (r < 0) return true;
    constexpr int RNG = 2 * CMID * KP;
    if (r >= RNG) return false;
    int n = r / KP, k = r - n * KP;
    float v = 0.f;
    if (k < CIN) {
        if (n < CMID) v = wa[k * CMID + n] - wa[(CIN + k) * CMID + n];
        else          v = wa[(CIN + k) * CMID + (n - CMID)];
    }
    u16 hi = f2b(v);
    dst[r] = hi;
    dst[RNG + r] = f2b(v - b2f(hi));
    return true;
}

__global__ __launch_bounds__(256) void prep_weights(
    const float* w1a, const float* w1b, const float* w2a, const float* w2b,
    const float* w3a, const float* w3b, const float* wf1, const float* wf2,
    const float* wf3,
    u16* t1uv, u16* t2uv, u16* t3uv, u16* t1b, u16* t2b, u16* t3b,
    u16* tf1, u16* tf2, u16* tf3)
{
    int t = blockIdx.x * 256 + threadIdx.x;
    if (seg_uv< 64,   3,  32>(t,      0, w1a, t1uv)) return;
    if (seg_uv< 64,  64,  64>(t,   4096, w2a, t2uv)) return;
    if (seg_uv<128, 128, 128>(t,  12288, w3a, t3uv)) return;
    if (seg< 64,  64,  64,  64>(t,  45056, w1b, t1b)) return;
    if (seg<128,  64,  64, 128>(t,  49152, w2b, t2b)) return;
    if (seg<512, 128, 128, 512>(t,  57344, w3b, t3b)) return;
    if (seg<512, 704, 704, 512>(t, 122880, wf1, tf1)) return;
    if (seg<256, 512, 512, 256>(t, 483328, wf2, tf2)) return;
    if (seg< 16, 256, 256,  12>(t, 614400, wf3, tf3)) return;
}

// ---------------------------------------------------------------------------
// kNN: one WAVE per point (4 points/WG), no LDS, no barriers.
// Key = (orderable(d2) << 11) | idx, exact in f64 (43 bits). 32 iterations of
// "min key strictly greater than last" == ascending selection with stable
// tie-break (lowest idx), matching lax.top_k. d2 in exact numpy op order.
// ---------------------------------------------------------------------------
__global__ __launch_bounds__(256) void knn_kernel(const float* __restrict__ pos,
                                                  int* __restrict__ idxout)
{
    int tid = threadIdx.x, lane = tid & 63, wv = tid >> 6;
    int p = blockIdx.x * 4 + wv;
    int b = p >> 11, n = p & 2047;
    const float* pb = pos + (size_t)b * 2048 * 3;
    float pn0 = pb[n * 3 + 0], pn1 = pb[n * 3 + 1], pn2 = pb[n * 3 + 2];
    float sqn = __fadd_rn(__fadd_rn(__fmul_rn(pn0, pn0), __fmul_rn(pn1, pn1)),
                          __fmul_rn(pn2, pn2));
    double kd[32];
#pragma unroll
    for (int j = 0; j < 32; ++j) {
        int m = lane + j * 64;
        float q0 = pb[m * 3 + 0], q1 = pb[m * 3 + 1], q2 = pb[m * 3 + 2];
        float sqm = __fadd_rn(__fadd_rn(__fmul_rn(q0, q0), __fmul_rn(q1, q1)),
                              __fmul_rn(q2, q2));
        float dot = __fadd_rn(__fadd_rn(__fmul_rn(pn0, q0), __fmul_rn(pn1, q1)),
                              __fmul_rn(pn2, q2));
        float d2 = __fadd_rn(__fsub_rn(sqn, __fmul_rn(2.0f, dot)), sqm);
        u32 u = __float_as_uint(d2);
        u = (u & 0x80000000u) ? ~u : (u | 0x80000000u);  // orderable
        kd[j] = (double)((((u64)u) << 11) | (u32)m);
    }
    double last = -1.0;
    for (int it = 0; it < 32; ++it) {
        double lm = 1e300;
#pragma unroll
        for (int j = 0; j < 32; ++j) {
            double t = kd[j];
            lm = fmin(lm, (t > last) ? t : 1e300);
        }
#pragma unroll
        for (int off = 32; off; off >>= 1)
            lm = fmin(lm, __shfl_xor(lm, off));
        if (lane == 0) idxout[(size_t)p * 32 + it] = (int)(((u64)lm) & 2047u);
        last = lm;
    }
}

// ---------------------------------------------------------------------------
// UV GEMM: out[n][0:CMID] = x@(Wa1-Wa2) + ba ; out[n][CMID:2CMID] = x@Wa2.
// A f32 -> split LDS, 3-term MFMA vs split weights, out stored split bf16.
// 32 rows / WG. N2 = 2*CMID.
// ---------------------------------------------------------------------------
template<int K, int KP, int N2>
__global__ __launch_bounds__(256) void uv_gemm(
    const float* __restrict__ xin, const u16* __restrict__ wT,
    const float* __restrict__ ba, u16* __restrict__ uvout)
{
    constexpr int SA = KP + 8;
    constexpr int WSZ = N2 * KP;
    constexpr size_t UVSZ = (size_t)16384 * N2;
    __shared__ __align__(16) u16 AsH[32 * SA];
    __shared__ __align__(16) u16 AsL[32 * SA];
    int row0 = blockIdx.x * 32;
    int tid = threadIdx.x, lane = tid & 63, wv = tid >> 6, ln = lane & 15, q = lane >> 4;

    for (int e = tid; e < 32 * (KP / 8); e += 256) {
        int r = e / (KP / 8), c0 = (e % (KP / 8)) * 8;
        bf16x8 hv, lv;
#pragma unroll
        for (int jj = 0; jj < 8; ++jj) {
            int c = c0 + jj;
            float v = (c < K) ? xin[(size_t)(row0 + r) * K + c] : 0.f;
            u16 hi = f2b(v);
            hv[jj] = hi;
            lv[jj] = f2b(v - b2f(hi));
        }
        *(bf16x8*)&AsH[r * SA + c0] = hv;
        *(bf16x8*)&AsL[r * SA + c0] = lv;
    }
    __syncthreads();

    constexpr int NT = N2 / 64;
    f32x4 acc[2][NT] = {};
    const int wbase = wv * (N2 / 4);
#pragma unroll
    for (int ks = 0; ks < KP / 32; ++ks) {
        bf16x8 a0h = *(const bf16x8*)&AsH[(ln) * SA + ks * 32 + q * 8];
        bf16x8 a1h = *(const bf16x8*)&AsH[(16 + ln) * SA + ks * 32 + q * 8];
        bf16x8 a0l = *(const bf16x8*)&AsL[(ln) * SA + ks * 32 + q * 8];
        bf16x8 a1l = *(const bf16x8*)&AsL[(16 + ln) * SA + ks * 32 + q * 8];
#pragma unroll
        for (int nt = 0; nt < NT; ++nt) {
            size_t wi = (size_t)(wbase + nt * 16 + ln) * KP + ks * 32 + q * 8;
            bf16x8 bh = *(const bf16x8*)&wT[wi];
            bf16x8 bl = *(const bf16x8*)&wT[WSZ + wi];
            acc[0][nt] = mfma16(a0h, bh, acc[0][nt]);
            acc[0][nt] = mfma16(a0h, bl, acc[0][nt]);
            acc[0][nt] = mfma16(a0l, bh, acc[0][nt]);
            acc[1][nt] = mfma16(a1h, bh, acc[1][nt]);
            acc[1][nt] = mfma16(a1h, bl, acc[1][nt]);
            acc[1][nt] = mfma16(a1l, bh, acc[1][nt]);
        }
    }
#pragma unroll
    for (int nt = 0; nt < NT; ++nt) {
        int col = wbase + nt * 16 + ln;
        float bv = (col < N2 / 2) ? ba[col] : 0.f;
#pragma unroll
        for (int mt = 0; mt < 2; ++mt)
#pragma unroll
            for (int r = 0; r < 4; ++r) {
                float v = acc[mt][nt][r] + bv;
                size_t o = (size_t)(row0 + mt * 16 + q * 4 + r) * N2 + col;
                u16 hi = f2b(v);
                uvout[o] = hi;
                uvout[UVSZ + o] = f2b(v - b2f(hi));
            }
    }
}

// ---------------------------------------------------------------------------
// Edge pool: 2 points per WG. h[r][c] = lrelu(U[p][c] + V[nbr[r]][c]) built
// as plain bf16 directly in MFMA A-fragment order in LDS; then
// [64 x CMID] @ Wb (split, 2-term) with per-point max over 32 rows,
// bias+lrelu epilogue. OUTB: write bf16, else f32.
// ---------------------------------------------------------------------------
template<int CMID, int COUT, bool OUTB>
__global__ __launch_bounds__(256) void edge_pool(
    const u16* __restrict__ uv, const int* __restrict__ idx,
    const u16* __restrict__ wbT, const float* __restrict__ bb,
    void* __restrict__ outp)
{
    constexpr int N2 = 2 * CMID;
    constexpr size_t UVSZ = (size_t)16384 * N2;
    constexpr int KC = CMID / 32;
    constexpr int WBSZ = COUT * CMID;
    constexpr int C8 = CMID / 8;
    __shared__ __align__(16) u16 hfrag[2 * 2 * KC * 512];  // [pt][mt][ks][lane][8]
    __shared__ int nbr[64];

    int tid = threadIdx.x, lane = tid & 63, wv = tid >> 6, ln = lane & 15, q = lane >> 4;
    int p0 = blockIdx.x * 2;

    if (tid < 64) {
        int pt = tid >> 5, kk = tid & 31;
        int p = p0 + pt;
        nbr[tid] = ((p >> 11) << 11) + (idx[(size_t)p * 32 + kk] & 2047);
    }
    __syncthreads();

    // build h in fragment order
    for (int e = tid; e < 2 * 32 * C8; e += 256) {
        int pt = e / (32 * C8), rem = e % (32 * C8), r = rem / C8, c8 = rem % C8;
        const u16* U = &uv[(size_t)(p0 + pt) * N2 + c8 * 8];
        const u16* V = &uv[(size_t)nbr[pt * 32 + r] * N2 + CMID + c8 * 8];
        bf16x8 uh = *(const bf16x8*)U, ul = *(const bf16x8*)(U + UVSZ);
        bf16x8 vh = *(const bf16x8*)V, vl = *(const bf16x8*)(V + UVSZ);
        bf16x8 hv;
#pragma unroll
        for (int jj = 0; jj < 8; ++jj) {
            float f = (b2f((u16)uh[jj]) + b2f((u16)ul[jj])) +
                      (b2f((u16)vh[jj]) + b2f((u16)vl[jj]));
            f = f >= 0.f ? f : 0.2f * f;
            hv[jj] = f2b(f);
        }
        int mt = r >> 4, lnr = r & 15, ks = c8 >> 2, qq = c8 & 3;
        *(bf16x8*)&hfrag[(((pt * 2 + mt) * KC + ks) * 64 + qq * 16 + lnr) * 8] = hv;
    }
    __syncthreads();

    constexpr int NTW = COUT / 64;
    f32x4 acc[2][2][NTW] = {};  // [pt][mt][nt]
    const int wbase = wv * (COUT / 4);
#pragma unroll
    for (int ks = 0; ks < KC; ++ks) {
        bf16x8 a[2][2];
#pragma unroll
        for (int pt = 0; pt < 2; ++pt)
#pragma unroll
            for (int mt = 0; mt < 2; ++mt)
                a[pt][mt] = *(const bf16x8*)&hfrag[(((pt * 2 + mt) * KC + ks) * 64 + lane) * 8];
#pragma unroll
        for (int nt = 0; nt < NTW; ++nt) {
            size_t wi = (size_t)(wbase + nt * 16 + ln) * CMID + ks * 32 + q * 8;
            bf16x8 bh = *(const bf16x8*)&wbT[wi];
            bf16x8 bl = *(const bf16x8*)&wbT[WBSZ + wi];
#pragma unroll
            for (int pt = 0; pt < 2; ++pt)
#pragma unroll
                for (int mt = 0; mt < 2; ++mt) {
                    acc[pt][mt][nt] = mfma16(a[pt][mt], bh, acc[pt][mt][nt]);
                    acc[pt][mt][nt] = mfma16(a[pt][mt], bl, acc[pt][mt][nt]);
                }
        }
    }
    // per-point max over 32 rows, bias+lrelu
#pragma unroll
    for (int pt = 0; pt < 2; ++pt)
#pragma unroll
        for (int nt = 0; nt < NTW; ++nt) {
            int col = wbase + nt * 16 + ln;
            float m = acc[pt][0][nt][0];
#pragma unroll
            for (int r = 1; r < 4; ++r) m = fmaxf(m, acc[pt][0][nt][r]);
#pragma unroll
            for (int r = 0; r < 4; ++r) m = fmaxf(m, acc[pt][1][nt][r]);
            m = fmaxf(m, __shfl_xor(m, 16));
            m = fmaxf(m, __shfl_xor(m, 32));
            if (q == 0) {
                float v = m + bb[col];
                v = v >= 0.f ? v : 0.2f * v;
                if constexpr (OUTB)
                    ((u16*)outp)[(size_t)(p0 + pt) * COUT + col] = f2b(v);
                else
                    ((float*)outp)[(size_t)(p0 + pt) * COUT + col] = v;
            }
        }
}

// ---------------------------------------------------------------------------
// head1: concat[x1(f32,64) | x2(f32,128) | x3(bf16,512)] (704) -> 512, lrelu,
// out bf16. 32 rows/WG, K tiled 2x352. 3-term for f32 cols (k<192), 2-term
// for exact-bf16 x3 cols.
// ---------------------------------------------------------------------------
__global__ __launch_bounds__(256) void head1(
    const float* __restrict__ x1, const float* __restrict__ x2,
    const u16* __restrict__ x3,
    const u16* __restrict__ wT, const float* __restrict__ bias,
    u16* __restrict__ out)
{
    constexpr int KD = 704, KT = 352, SA = 360, COUT = 512;
    constexpr int WSZ = 512 * 704;
    __shared__ __align__(16) u16 AsH[32 * SA];
    __shared__ __align__(16) u16 AsL[32 * SA];
    int row0 = blockIdx.x * 32;
    int tid = threadIdx.x, lane = tid & 63, wv = tid >> 6, ln = lane & 15, q = lane >> 4;

    f32x4 acc[2][8] = {};
    const int wbase = wv * 128;

    for (int ph = 0; ph < 2; ++ph) {
        if (ph) __syncthreads();
        for (int e = tid; e < 32 * 44; e += 256) {
            int r = e / 44, c8l = e % 44;
            int c = ph * KT + c8l * 8;
            int g = row0 + r;
            int a = r * SA + c8l * 8;
            if (c < 192) {
                const float* src = (c < 64) ? &x1[(size_t)g * 64 + c]
                                            : &x2[(size_t)g * 128 + (c - 64)];
                bf16x8 hv, lv;
#pragma unroll
                for (int jj = 0; jj < 8; ++jj) {
                    float v = src[jj];
                    u16 hi = f2b(v);
                    hv[jj] = hi;
                    lv[jj] = f2b(v - b2f(hi));
                }
                *(bf16x8*)&AsH[a] = hv;
                *(bf16x8*)&AsL[a] = lv;
            } else {
                *(bf16x8*)&AsH[a] = *(const bf16x8*)&x3[(size_t)g * 512 + (c - 192)];
                bf16x8 z = {0, 0, 0, 0, 0, 0, 0, 0};
                *(bf16x8*)&AsL[a] = z;
            }
        }
        __syncthreads();
        for (int ks = 0; ks < 11; ++ks) {
            int gk = ph * 11 + ks;
            bool t3 = (gk < 6);
            bf16x8 a0h = *(const bf16x8*)&AsH[(ln) * SA + ks * 32 + q * 8];
            bf16x8 a1h = *(const bf16x8*)&AsH[(16 + ln) * SA + ks * 32 + q * 8];
            bf16x8 a0l = *(const bf16x8*)&AsL[(ln) * SA + ks * 32 + q * 8];
            bf16x8 a1l = *(const bf16x8*)&AsL[(16 + ln) * SA + ks * 32 + q * 8];
#pragma unroll
            for (int nt = 0; nt < 8; ++nt) {
                size_t wi = (size_t)(wbase + nt * 16 + ln) * KD + gk * 32 + q * 8;
                bf16x8 bh = *(const bf16x8*)&wT[wi];
                bf16x8 bl = *(const bf16x8*)&wT[WSZ + wi];
                acc[0][nt] = mfma16(a0h, bh, acc[0][nt]);
                acc[0][nt] = mfma16(a0h, bl, acc[0][nt]);
                acc[1][nt] = mfma16(a1h, bh, acc[1][nt]);
                acc[1][nt] = mfma16(a1h, bl, acc[1][nt]);
                if (t3) {
                    acc[0][nt] = mfma16(a0l, bh, acc[0][nt]);
                    acc[1][nt] = mfma16(a1l, bh, acc[1][nt]);
                }
            }
        }
    }
#pragma unroll
    for (int nt = 0; nt < 8; ++nt) {
        int col = wbase + nt * 16 + ln;
        float bv = bias[col];
#pragma unroll
        for (int mt = 0; mt < 2; ++mt)
#pragma unroll
            for (int r = 0; r < 4; ++r) {
                float v = acc[mt][nt][r] + bv;
                v = v >= 0.f ? v : 0.2f * v;
                out[(size_t)(row0 + mt * 16 + q * 4 + r) * COUT + col] = f2b(v);
            }
    }
}

// ---------------------------------------------------------------------------
// head_bf: A bf16 [16384][K] -> COUT, split W 2-term, optional lrelu,
// out bf16. 32 rows/WG.
// ---------------------------------------------------------------------------
template<int K, int COUT>
__global__ __launch_bounds__(256) void head_bf(
    const u16* __restrict__ A, const u16* __restrict__ wT,
    const float* __restrict__ bias, u16* __restrict__ out)
{
    constexpr int SA = K + 8;
    constexpr int WSZ = COUT * K;
    __shared__ __align__(16) u16 As[32 * SA];
    int row0 = blockIdx.x * 32;
    int tid = threadIdx.x, lane = tid & 63, wv = tid >> 6, ln = lane & 15, q = lane >> 4;

    for (int e = tid; e < 32 * (K / 8); e += 256) {
        int r = e / (K / 8), c0 = (e % (K / 8)) * 8;
        *(bf16x8*)&As[r * SA + c0] = *(const bf16x8*)&A[(size_t)(row0 + r) * K + c0];
    }
    __syncthreads();

    constexpr int NT = COUT / 64;
    f32x4 acc[2][NT] = {};
    const int wbase = wv * (COUT / 4);
    for (int ks = 0; ks < K / 32; ++ks) {
        bf16x8 a0 = *(const bf16x8*)&As[(ln) * SA + ks * 32 + q * 8];
        bf16x8 a1 = *(const bf16x8*)&As[(16 + ln) * SA + ks * 32 + q * 8];
#pragma unroll
        for (int nt = 0; nt < NT; ++nt) {
            size_t wi = (size_t)(wbase + nt * 16 + ln) * K + ks * 32 + q * 8;
            bf16x8 bh = *(const bf16x8*)&wT[wi];
            bf16x8 bl = *(const bf16x8*)&wT[WSZ + wi];
            acc[0][nt] = mfma16(a0, bh, acc[0][nt]);
            acc[0][nt] = mfma16(a0, bl, acc[0][nt]);
            acc[1][nt] = mfma16(a1, bh, acc[1][nt]);
            acc[1][nt] = mfma16(a1, bl, acc[1][nt]);
        }
    }
#pragma unroll
    for (int nt = 0; nt < NT; ++nt) {
        int col = wbase + nt * 16 + ln;
        float bv = bias[col];
#pragma unroll
        for (int mt = 0; mt < 2; ++mt)
#pragma unroll
            for (int r = 0; r < 4; ++r) {
                float v = acc[mt][nt][r] + bv;
                v = v >= 0.f ? v : 0.2f * v;
                out[(size_t)(row0 + mt * 16 + q * 4 + r) * COUT + col] = f2b(v);
            }
    }
}

// ---------------------------------------------------------------------------
// head3: A bf16 [16384][256] -> 12 (N padded 16), split W 2-term, out f32.
// One wave per 32-row strip.
// ---------------------------------------------------------------------------
__global__ __launch_bounds__(256) void head_gemm3(
    const u16* __restrict__ A, const u16* __restrict__ wT,
    const float* __restrict__ bias, float* __restrict__ out)
{
    constexpr int WSZ = 16 * 256;
    int tid = threadIdx.x, lane = tid & 63, wv = tid >> 6, ln = lane & 15, q = lane >> 4;
    int row0 = (blockIdx.x * 4 + wv) * 32;
    f32x4 acc[2] = {};
#pragma unroll
    for (int ks = 0; ks < 8; ++ks) {
        bf16x8 a0 = *(const bf16x8*)&A[(size_t)(row0 + ln) * 256 + ks * 32 + q * 8];
        bf16x8 a1 = *(const bf16x8*)&A[(size_t)(row0 + 16 + ln) * 256 + ks * 32 + q * 8];
        size_t wi = (size_t)ln * 256 + ks * 32 + q * 8;
        bf16x8 bh = *(const bf16x8*)&wT[wi];
        bf16x8 bl = *(const bf16x8*)&wT[WSZ + wi];
        acc[0] = mfma16(a0, bh, acc[0]);
        acc[0] = mfma16(a0, bl, acc[0]);
        acc[1] = mfma16(a1, bh, acc[1]);
        acc[1] = mfma16(a1, bl, acc[1]);
    }
    if (ln < 12) {
        float bv = bias[ln];
#pragma unroll
        for (int mt = 0; mt < 2; ++mt)
#pragma unroll
            for (int r = 0; r < 4; ++r)
                out[(size_t)(row0 + mt * 16 + q * 4 + r) * 12 + ln] = acc[mt][r] + bv;
    }
}

// ---------------------------------------------------------------------------
// Workspace (peak 50,708,480 B = 48.4 MB; proven safe <= 52.8 MB):
//   [0,        2473984)  split weights
//   [2473984,  4571136)  idxb
//   [4571136,  8765440)  x1 f32      (dead after head1; h2 bf16 overlays)
//   [8765440, 17154048)  x2 f32      (dead after head1)
//   [17154048,33931264)  uv scratch (uv1/uv2/uv3 sequential; h1 bf16 overlays)
//   [33931264,50708480)  x3 bf16
// ---------------------------------------------------------------------------
extern "C" void kernel_launch(void* const* d_in, const int* in_sizes, int n_in,
                              void* d_out, int out_size, void* d_ws, size_t ws_size,
                              hipStream_t stream)
{
    (void)in_sizes; (void)n_in; (void)out_size; (void)ws_size;
    const float* x   = (const float*)d_in[0];
    const float* pos = (const float*)d_in[1];
    const float* w1a = (const float*)d_in[2];  const float* b1a = (const float*)d_in[3];
    const float* w1b = (const float*)d_in[4];  const float* b1b = (const float*)d_in[5];
    const float* w2a = (const float*)d_in[6];  const float* b2a = (const float*)d_in[7];
    const float* w2b = (const float*)d_in[8];  const float* b2b = (const float*)d_in[9];
    const float* w3a = (const float*)d_in[10]; const float* b3a = (const float*)d_in[11];
    const float* w3b = (const float*)d_in[12]; const float* b3b = (const float*)d_in[13];
    const float* wf1 = (const float*)d_in[14]; const float* bf1 = (const float*)d_in[15];
    const float* wf2 = (const float*)d_in[16]; const float* bf2 = (const float*)d_in[17];
    const float* wf3 = (const float*)d_in[18]; const float* bf3 = (const float*)d_in[19];

    char* ws = (char*)d_ws;
    u16* t1uv = (u16*)(ws + 0);
    u16* t2uv = (u16*)(ws + 16384);
    u16* t3uv = (u16*)(ws + 49152);
    u16* t1b  = (u16*)(ws + 180224);
    u16* t2b  = (u16*)(ws + 196608);
    u16* t3b  = (u16*)(ws + 229376);
    u16* tf1  = (u16*)(ws + 491520);
    u16* tf2  = (u16*)(ws + 1933312);
    u16* tf3  = (u16*)(ws + 2457600);
    int*   idxb = (int*)(ws + 2473984);
    float* x1 = (float*)(ws + 4571136);
    float* x2 = (float*)(ws + 8765440);
    u16*   uvs = (u16*)(ws + 17154048);
    u16*   x3 = (u16*)(ws + 33931264);
    u16*   h1 = uvs;                      // overlays uv scratch after edge3
    u16*   h2 = (u16*)(ws + 4571136);     // overlays x1/x2 after head1

    prep_weights<<<2416, 256, 0, stream>>>(w1a, w1b, w2a, w2b, w3a, w3b, wf1, wf2, wf3,
                                           t1uv, t2uv, t3uv, t1b, t2b, t3b, tf1, tf2, tf3);
    knn_kernel<<<4096, 256, 0, stream>>>(pos, idxb);
    uv_gemm<  3, 32, 128><<<512, 256, 0, stream>>>(x,  t1uv, b1a, uvs);
    edge_pool< 64,  64, false><<<8192, 256, 0, stream>>>(uvs, idxb, t1b, b1b, x1);
    uv_gemm< 64, 64, 128><<<512, 256, 0, stream>>>(x1, t2uv, b2a, uvs);
    edge_pool< 64, 128, false><<<8192, 256, 0, stream>>>(uvs, idxb, t2b, b2b, x2);
    uv_gemm<128, 128, 256><<<512, 256, 0, stream>>>(x2, t3uv, b3a, uvs);
    edge_pool<128, 512, true><<<8192, 256, 0, stream>>>(uvs, idxb, t3b, b3b, x3);
    head1<<<512, 256, 0, stream>>>(x1, x2, x3, tf1, bf1, h1);
    head_bf<512, 256><<<512, 256, 0, stream>>>(h1, tf2, bf2, h2);
    head_gemm3<<<128, 256, 0, stream>>>(h2, tf3, bf3, (float*)d_out);
}

// Round 6
// 796.619 us; speedup vs baseline: 2.0571x; 1.2034x over previous
//
#include <hip/hip_runtime.h>

typedef unsigned short u16;
typedef unsigned int u32;
typedef unsigned long long u64;
typedef short bf16x8 __attribute__((ext_vector_type(8)));
typedef float f32x4 __attribute__((ext_vector_type(4)));

__device__ __forceinline__ float b2f(u16 u) {
    return __uint_as_float(((u32)u) << 16);
}
__device__ __forceinline__ u16 f2b(float f) {  // RNE
    u32 u = __float_as_uint(f);
    u32 r = u + 0x7fffu + ((u >> 16) & 1u);
    return (u16)(r >> 16);
}
__device__ __forceinline__ f32x4 mfma16(bf16x8 a, bf16x8 b, f32x4 c) {
    return __builtin_amdgcn_mfma_f32_16x16x32_bf16(a, b, c, 0, 0, 0);
}

// ---------------------------------------------------------------------------
// prep: weights transposed W^T[n][k], split bf16 (hi plane then lo plane).
// ---------------------------------------------------------------------------
template<int NP, int KP, int R, int C>
__device__ __forceinline__ bool seg(int t, int base, const float* src, u16* dst) {
    int r = t - base;
    if (r < 0) return true;
    constexpr int RNG = NP * KP;
    if (r >= RNG) return false;
    int n = r / KP, k = r - n * KP;
    float v = (k < R && n < C) ? src[k * C + n] : 0.f;
    u16 hi = f2b(v);
    dst[r] = hi;
    dst[RNG + r] = f2b(v - b2f(hi));
    return true;
}
// seg_uv: stacked [(Wa1-Wa2)^T ; Wa2^T] shape [2*CMID][KP] from wa[2*CIN][CMID].
template<int CMID, int CIN, int KP>
__device__ __forceinline__ bool seg_uv(int t, int base, const float* wa, u16* dst) {
    int r = t - base;
    if (r < 0) return true;
    constexpr int RNG = 2 * CMID * KP;
    if (r >= RNG) return false;
    int n = r / KP, k = r - n * KP;
    float v = 0.f;
    if (k < CIN) {
        if (n < CMID) v = wa[k * CMID + n] - wa[(CIN + k) * CMID + n];
        else          v = wa[(CIN + k) * CMID + (n - CMID)];
    }
    u16 hi = f2b(v);
    dst[r] = hi;
    dst[RNG + r] = f2b(v - b2f(hi));
    return true;
}

__global__ __launch_bounds__(256) void prep_weights(
    const float* w1a, const float* w1b, const float* w2a, const float* w2b,
    const float* w3a, const float* w3b, const float* wf1, const float* wf2,
    const float* wf3,
    u16* t1uv, u16* t2uv, u16* t3uv, u16* t1b, u16* t2b, u16* t3b,
    u16* tf1, u16* tf2, u16* tf3)
{
    int t = blockIdx.x * 256 + threadIdx.x;
    if (seg_uv< 64,   3,  32>(t,      0, w1a, t1uv)) return;
    if (seg_uv< 64,  64,  64>(t,   4096, w2a, t2uv)) return;
    if (seg_uv<128, 128, 128>(t,  12288, w3a, t3uv)) return;
    if (seg< 64,  64,  64,  64>(t,  45056, w1b, t1b)) return;
    if (seg<128,  64,  64, 128>(t,  49152, w2b, t2b)) return;
    if (seg<512, 128, 128, 512>(t,  57344, w3b, t3b)) return;
    if (seg<512, 704, 704, 512>(t, 122880, wf1, tf1)) return;
    if (seg<256, 512, 512, 256>(t, 483328, wf2, tf2)) return;
    if (seg< 16, 256, 256,  12>(t, 614400, wf3, tf3)) return;
}

// ---------------------------------------------------------------------------
// kNN: one WAVE per point. Key = (orderable(d2) << 11) | idx, exact in f64.
// 32 iterations of ascending min-above-last == stable top-k (lowest idx ties).
// ---------------------------------------------------------------------------
__global__ __launch_bounds__(256) void knn_kernel(const float* __restrict__ pos,
                                                  int* __restrict__ idxout)
{
    int tid = threadIdx.x, lane = tid & 63, wv = tid >> 6;
    int p = blockIdx.x * 4 + wv;
    int b = p >> 11, n = p & 2047;
    const float* pb = pos + (size_t)b * 2048 * 3;
    float pn0 = pb[n * 3 + 0], pn1 = pb[n * 3 + 1], pn2 = pb[n * 3 + 2];
    float sqn = __fadd_rn(__fadd_rn(__fmul_rn(pn0, pn0), __fmul_rn(pn1, pn1)),
                          __fmul_rn(pn2, pn2));
    double kd[32];
#pragma unroll
    for (int j = 0; j < 32; ++j) {
        int m = lane + j * 64;
        float q0 = pb[m * 3 + 0], q1 = pb[m * 3 + 1], q2 = pb[m * 3 + 2];
        float sqm = __fadd_rn(__fadd_rn(__fmul_rn(q0, q0), __fmul_rn(q1, q1)),
                              __fmul_rn(q2, q2));
        float dot = __fadd_rn(__fadd_rn(__fmul_rn(pn0, q0), __fmul_rn(pn1, q1)),
                              __fmul_rn(pn2, q2));
        float d2 = __fadd_rn(__fsub_rn(sqn, __fmul_rn(2.0f, dot)), sqm);
        u32 u = __float_as_uint(d2);
        u = (u & 0x80000000u) ? ~u : (u | 0x80000000u);  // orderable
        kd[j] = (double)((((u64)u) << 11) | (u32)m);
    }
    double last = -1.0;
    for (int it = 0; it < 32; ++it) {
        double lm = 1e300;
#pragma unroll
        for (int j = 0; j < 32; ++j) {
            double t = kd[j];
            lm = fmin(lm, (t > last) ? t : 1e300);
        }
#pragma unroll
        for (int off = 32; off; off >>= 1)
            lm = fmin(lm, __shfl_xor(lm, off));
        if (lane == 0) idxout[(size_t)p * 32 + it] = (int)(((u64)lm) & 2047u);
        last = lm;
    }
}

// ---------------------------------------------------------------------------
// UV GEMM: uvout[n][0:CMID] = x@(Wa1-Wa2)+ba ; uvout[n][CMID:2CMID] = x@Wa2.
// A f32 -> split LDS, 3-term MFMA vs split weights, out f32 (exact).
// ---------------------------------------------------------------------------
template<int K, int KP, int N2>
__global__ __launch_bounds__(256) void uv_gemm(
    const float* __restrict__ xin, const u16* __restrict__ wT,
    const float* __restrict__ ba, float* __restrict__ uvout)
{
    constexpr int SA = KP + 8;
    constexpr int WSZ = N2 * KP;
    __shared__ __align__(16) u16 AsH[32 * SA];
    __shared__ __align__(16) u16 AsL[32 * SA];
    int row0 = blockIdx.x * 32;
    int tid = threadIdx.x, lane = tid & 63, wv = tid >> 6, ln = lane & 15, q = lane >> 4;

    for (int e = tid; e < 32 * (KP / 8); e += 256) {
        int r = e / (KP / 8), c0 = (e % (KP / 8)) * 8;
        bf16x8 hv, lv;
#pragma unroll
        for (int jj = 0; jj < 8; ++jj) {
            int c = c0 + jj;
            float v = (c < K) ? xin[(size_t)(row0 + r) * K + c] : 0.f;
            u16 hi = f2b(v);
            hv[jj] = hi;
            lv[jj] = f2b(v - b2f(hi));
        }
        *(bf16x8*)&AsH[r * SA + c0] = hv;
        *(bf16x8*)&AsL[r * SA + c0] = lv;
    }
    __syncthreads();

    constexpr int NT = N2 / 64;
    f32x4 acc[2][NT] = {};
    const int wbase = wv * (N2 / 4);
#pragma unroll
    for (int ks = 0; ks < KP / 32; ++ks) {
        bf16x8 a0h = *(const bf16x8*)&AsH[(ln) * SA + ks * 32 + q * 8];
        bf16x8 a1h = *(const bf16x8*)&AsH[(16 + ln) * SA + ks * 32 + q * 8];
        bf16x8 a0l = *(const bf16x8*)&AsL[(ln) * SA + ks * 32 + q * 8];
        bf16x8 a1l = *(const bf16x8*)&AsL[(16 + ln) * SA + ks * 32 + q * 8];
#pragma unroll
        for (int nt = 0; nt < NT; ++nt) {
            size_t wi = (size_t)(wbase + nt * 16 + ln) * KP + ks * 32 + q * 8;
            bf16x8 bh = *(const bf16x8*)&wT[wi];
            bf16x8 bl = *(const bf16x8*)&wT[WSZ + wi];
            acc[0][nt] = mfma16(a0h, bh, acc[0][nt]);
            acc[0][nt] = mfma16(a0h, bl, acc[0][nt]);
            acc[0][nt] = mfma16(a0l, bh, acc[0][nt]);
            acc[1][nt] = mfma16(a1h, bh, acc[1][nt]);
            acc[1][nt] = mfma16(a1h, bl, acc[1][nt]);
            acc[1][nt] = mfma16(a1l, bh, acc[1][nt]);
        }
    }
#pragma unroll
    for (int nt = 0; nt < NT; ++nt) {
        int col = wbase + nt * 16 + ln;
        float bv = (col < N2 / 2) ? ba[col] : 0.f;
#pragma unroll
        for (int mt = 0; mt < 2; ++mt)
#pragma unroll
            for (int r = 0; r < 4; ++r)
                uvout[(size_t)(row0 + mt * 16 + q * 4 + r) * N2 + col] =
                    acc[mt][nt][r] + bv;
    }
}

// ---------------------------------------------------------------------------
// Edge pool: 2 points/WG. h[r][c] = lrelu(U[p][c]+V[nbr_r][c]) -> bf16 in
// XOR-swizzled MFMA A-fragment order in LDS; then column-group passes of NTP
// tiles: [64 x CMID] @ Wb (split, 2-term), per-point max over 32 rows,
// bias+lrelu. Pass structure keeps live acc at 8 f32x4 -> 3 waves/SIMD.
// ---------------------------------------------------------------------------
template<int CMID, int COUT, bool OUTB, int NTP>
__global__ __launch_bounds__(256, 3) void edge_pool(
    const float* __restrict__ uvf, const int* __restrict__ idx,
    const u16* __restrict__ wbT, const float* __restrict__ bb,
    void* __restrict__ outp)
{
    constexpr int N2 = 2 * CMID;
    constexpr int KC = CMID / 32;
    constexpr int WBSZ = COUT * CMID;
    constexpr int C8 = CMID / 8;
    __shared__ __align__(16) u16 hfrag[2 * 2 * KC * 512];  // [pt][mt][ks][slot][8]
    __shared__ int nbr[64];

    int tid = threadIdx.x, lane = tid & 63, wv = tid >> 6, ln = lane & 15, q = lane >> 4;
    int p0 = blockIdx.x * 2;

    if (tid < 64) {
        int pt = tid >> 5, kk = tid & 31;
        int p = p0 + pt;
        nbr[tid] = ((p >> 11) << 11) + (idx[(size_t)p * 32 + kk] & 2047);
    }
    __syncthreads();

    // build h in swizzled fragment order
    for (int e = tid; e < 2 * 32 * C8; e += 256) {
        int pt = e / (32 * C8), rem = e % (32 * C8), r = rem / C8, c8 = rem % C8;
        const float* U = &uvf[(size_t)(p0 + pt) * N2 + c8 * 8];
        const float* V = &uvf[(size_t)nbr[pt * 32 + r] * N2 + CMID + c8 * 8];
        bf16x8 hv;
#pragma unroll
        for (int jj = 0; jj < 8; ++jj) {
            float f = U[jj] + V[jj];
            f = f >= 0.f ? f : 0.2f * f;
            hv[jj] = f2b(f);
        }
        int mt = r >> 4, lnr = r & 15, ks = c8 >> 2, qq = c8 & 3;
        int slot = qq * 16 + (lnr ^ ((ks << 2) | qq));
        *(bf16x8*)&hfrag[(((pt * 2 + mt) * KC + ks) * 64 + slot) * 8] = hv;
    }
    __syncthreads();

    constexpr int NTW = COUT / 64;
    const int wbase = wv * (COUT / 4);
    for (int ng = 0; ng < NTW; ng += NTP) {
        f32x4 acc[2][2][NTP] = {};  // [pt][mt][nt]
        for (int ks = 0; ks < KC; ++ks) {
            bf16x8 a[2][2];
            int slot = q * 16 + (ln ^ ((ks << 2) | q));
#pragma unroll
            for (int pt = 0; pt < 2; ++pt)
#pragma unroll
                for (int mt = 0; mt < 2; ++mt)
                    a[pt][mt] = *(const bf16x8*)
                        &hfrag[(((pt * 2 + mt) * KC + ks) * 64 + slot) * 8];
#pragma unroll
            for (int nt = 0; nt < NTP; ++nt) {
                size_t wi = (size_t)(wbase + (ng + nt) * 16 + ln) * CMID + ks * 32 + q * 8;
                bf16x8 bh = *(const bf16x8*)&wbT[wi];
                bf16x8 bl = *(const bf16x8*)&wbT[WBSZ + wi];
#pragma unroll
                for (int pt = 0; pt < 2; ++pt)
#pragma unroll
                    for (int mt = 0; mt < 2; ++mt) {
                        acc[pt][mt][nt] = mfma16(a[pt][mt], bh, acc[pt][mt][nt]);
                        acc[pt][mt][nt] = mfma16(a[pt][mt], bl, acc[pt][mt][nt]);
                    }
            }
        }
        // per-point max over 32 rows, bias+lrelu, store (frees accs)
#pragma unroll
        for (int pt = 0; pt < 2; ++pt)
#pragma unroll
            for (int nt = 0; nt < NTP; ++nt) {
                int col = wbase + (ng + nt) * 16 + ln;
                float m = acc[pt][0][nt][0];
#pragma unroll
                for (int r = 1; r < 4; ++r) m = fmaxf(m, acc[pt][0][nt][r]);
#pragma unroll
                for (int r = 0; r < 4; ++r) m = fmaxf(m, acc[pt][1][nt][r]);
                m = fmaxf(m, __shfl_xor(m, 16));
                m = fmaxf(m, __shfl_xor(m, 32));
                if (q == 0) {
                    float v = m + bb[col];
                    v = v >= 0.f ? v : 0.2f * v;
                    if constexpr (OUTB)
                        ((u16*)outp)[(size_t)(p0 + pt) * COUT + col] = f2b(v);
                    else
                        ((float*)outp)[(size_t)(p0 + pt) * COUT + col] = v;
                }
            }
    }
}

// ---------------------------------------------------------------------------
// head1: concat[x1(f32,64)|x2(f32,128)|x3(bf16,512)] (704) -> 512, lrelu,
// out bf16. 32 rows/WG, K tiled 2x352. 3-term for f32 cols, 2-term for x3.
// ---------------------------------------------------------------------------
__global__ __launch_bounds__(256) void head1(
    const float* __restrict__ x1, const float* __restrict__ x2,
    const u16* __restrict__ x3,
    const u16* __restrict__ wT, const float* __restrict__ bias,
    u16* __restrict__ out)
{
    constexpr int KD = 704, KT = 352, SA = 360, COUT = 512;
    constexpr int WSZ = 512 * 704;
    __shared__ __align__(16) u16 AsH[32 * SA];
    __shared__ __align__(16) u16 AsL[32 * SA];
    int row0 = blockIdx.x * 32;
    int tid = threadIdx.x, lane = tid & 63, wv = tid >> 6, ln = lane & 15, q = lane >> 4;

    f32x4 acc[2][8] = {};
    const int wbase = wv * 128;

    for (int ph = 0; ph < 2; ++ph) {
        if (ph) __syncthreads();
        for (int e = tid; e < 32 * 44; e += 256) {
            int r = e / 44, c8l = e % 44;
            int c = ph * KT + c8l * 8;
            int g = row0 + r;
            int a = r * SA + c8l * 8;
            if (c < 192) {
                const float* src = (c < 64) ? &x1[(size_t)g * 64 + c]
                                            : &x2[(size_t)g * 128 + (c - 64)];
                bf16x8 hv, lv;
#pragma unroll
                for (int jj = 0; jj < 8; ++jj) {
                    float v = src[jj];
                    u16 hi = f2b(v);
                    hv[jj] = hi;
                    lv[jj] = f2b(v - b2f(hi));
                }
                *(bf16x8*)&AsH[a] = hv;
                *(bf16x8*)&AsL[a] = lv;
            } else {
                *(bf16x8*)&AsH[a] = *(const bf16x8*)&x3[(size_t)g * 512 + (c - 192)];
                bf16x8 z = {0, 0, 0, 0, 0, 0, 0, 0};
                *(bf16x8*)&AsL[a] = z;
            }
        }
        __syncthreads();
        for (int ks = 0; ks < 11; ++ks) {
            int gk = ph * 11 + ks;
            bool t3 = (gk < 6);
            bf16x8 a0h = *(const bf16x8*)&AsH[(ln) * SA + ks * 32 + q * 8];
            bf16x8 a1h = *(const bf16x8*)&AsH[(16 + ln) * SA + ks * 32 + q * 8];
            bf16x8 a0l = *(const bf16x8*)&AsL[(ln) * SA + ks * 32 + q * 8];
            bf16x8 a1l = *(const bf16x8*)&AsL[(16 + ln) * SA + ks * 32 + q * 8];
#pragma unroll
            for (int nt = 0; nt < 8; ++nt) {
                size_t wi = (size_t)(wbase + nt * 16 + ln) * KD + gk * 32 + q * 8;
                bf16x8 bh = *(const bf16x8*)&wT[wi];
                bf16x8 bl = *(const bf16x8*)&wT[WSZ + wi];
                acc[0][nt] = mfma16(a0h, bh, acc[0][nt]);
                acc[0][nt] = mfma16(a0h, bl, acc[0][nt]);
                acc[1][nt] = mfma16(a1h, bh, acc[1][nt]);
                acc[1][nt] = mfma16(a1h, bl, acc[1][nt]);
                if (t3) {
                    acc[0][nt] = mfma16(a0l, bh, acc[0][nt]);
                    acc[1][nt] = mfma16(a1l, bh, acc[1][nt]);
                }
            }
        }
    }
#pragma unroll
    for (int nt = 0; nt < 8; ++nt) {
        int col = wbase + nt * 16 + ln;
        float bv = bias[col];
#pragma unroll
        for (int mt = 0; mt < 2; ++mt)
#pragma unroll
            for (int r = 0; r < 4; ++r) {
                float v = acc[mt][nt][r] + bv;
                v = v >= 0.f ? v : 0.2f * v;
                out[(size_t)(row0 + mt * 16 + q * 4 + r) * COUT + col] = f2b(v);
            }
    }
}

// ---------------------------------------------------------------------------
// head_bf: A bf16 [16384][K] -> COUT, split W 2-term, lrelu, out bf16.
// ---------------------------------------------------------------------------
template<int K, int COUT>
__global__ __launch_bounds__(256) void head_bf(
    const u16* __restrict__ A, const u16* __restrict__ wT,
    const float* __restrict__ bias, u16* __restrict__ out)
{
    constexpr int SA = K + 8;
    constexpr int WSZ = COUT * K;
    __shared__ __align__(16) u16 As[32 * SA];
    int row0 = blockIdx.x * 32;
    int tid = threadIdx.x, lane = tid & 63, wv = tid >> 6, ln = lane & 15, q = lane >> 4;

    for (int e = tid; e < 32 * (K / 8); e += 256) {
        int r = e / (K / 8), c0 = (e % (K / 8)) * 8;
        *(bf16x8*)&As[r * SA + c0] = *(const bf16x8*)&A[(size_t)(row0 + r) * K + c0];
    }
    __syncthreads();

    constexpr int NT = COUT / 64;
    f32x4 acc[2][NT] = {};
    const int wbase = wv * (COUT / 4);
    for (int ks = 0; ks < K / 32; ++ks) {
        bf16x8 a0 = *(const bf16x8*)&As[(ln) * SA + ks * 32 + q * 8];
        bf16x8 a1 = *(const bf16x8*)&As[(16 + ln) * SA + ks * 32 + q * 8];
#pragma unroll
        for (int nt = 0; nt < NT; ++nt) {
            size_t wi = (size_t)(wbase + nt * 16 + ln) * K + ks * 32 + q * 8;
            bf16x8 bh = *(const bf16x8*)&wT[wi];
            bf16x8 bl = *(const bf16x8*)&wT[WSZ + wi];
            acc[0][nt] = mfma16(a0, bh, acc[0][nt]);
            acc[0][nt] = mfma16(a0, bl, acc[0][nt]);
            acc[1][nt] = mfma16(a1, bh, acc[1][nt]);
            acc[1][nt] = mfma16(a1, bl, acc[1][nt]);
        }
    }
#pragma unroll
    for (int nt = 0; nt < NT; ++nt) {
        int col = wbase + nt * 16 + ln;
        float bv = bias[col];
#pragma unroll
        for (int mt = 0; mt < 2; ++mt)
#pragma unroll
            for (int r = 0; r < 4; ++r) {
                float v = acc[mt][nt][r] + bv;
                v = v >= 0.f ? v : 0.2f * v;
                out[(size_t)(row0 + mt * 16 + q * 4 + r) * COUT + col] = f2b(v);
            }
    }
}

// ---------------------------------------------------------------------------
// head3: A bf16 [16384][256] -> 12 (N padded 16), split W 2-term, out f32.
// ---------------------------------------------------------------------------
__global__ __launch_bounds__(256) void head_gemm3(
    const u16* __restrict__ A, const u16* __restrict__ wT,
    const float* __restrict__ bias, float* __restrict__ out)
{
    constexpr int WSZ = 16 * 256;
    int tid = threadIdx.x, lane = tid & 63, wv = tid >> 6, ln = lane & 15, q = lane >> 4;
    int row0 = (blockIdx.x * 4 + wv) * 32;
    f32x4 acc[2] = {};
#pragma unroll
    for (int ks = 0; ks < 8; ++ks) {
        bf16x8 a0 = *(const bf16x8*)&A[(size_t)(row0 + ln) * 256 + ks * 32 + q * 8];
        bf16x8 a1 = *(const bf16x8*)&A[(size_t)(row0 + 16 + ln) * 256 + ks * 32 + q * 8];
        size_t wi = (size_t)ln * 256 + ks * 32 + q * 8;
        bf16x8 bh = *(const bf16x8*)&wT[wi];
        bf16x8 bl = *(const bf16x8*)&wT[WSZ + wi];
        acc[0] = mfma16(a0, bh, acc[0]);
        acc[0] = mfma16(a0, bl, acc[0]);
        acc[1] = mfma16(a1, bh, acc[1]);
        acc[1] = mfma16(a1, bl, acc[1]);
    }
    if (ln < 12) {
        float bv = bias[ln];
#pragma unroll
        for (int mt = 0; mt < 2; ++mt)
#pragma unroll
            for (int r = 0; r < 4; ++r)
                out[(size_t)(row0 + mt * 16 + q * 4 + r) * 12 + ln] = acc[mt][r] + bv;
    }
}

// ---------------------------------------------------------------------------
// Workspace (peak 50,708,480 B = 48.4 MB):
//   [0,        2473984)  split weights
//   [2473984,  4571136)  idxb
//   [4571136,  8765440)  x1 f32      (dead after head1; h2 bf16 overlays)
//   [8765440, 17154048)  x2 f32      (dead after head1)
//   [17154048,33931264)  uv f32 scratch (h1 bf16 overlays after edge3)
//   [33931264,50708480)  x3 bf16
// ---------------------------------------------------------------------------
extern "C" void kernel_launch(void* const* d_in, const int* in_sizes, int n_in,
                              void* d_out, int out_size, void* d_ws, size_t ws_size,
                              hipStream_t stream)
{
    (void)in_sizes; (void)n_in; (void)out_size; (void)ws_size;
    const float* x   = (const float*)d_in[0];
    const float* pos = (const float*)d_in[1];
    const float* w1a = (const float*)d_in[2];  const float* b1a = (const float*)d_in[3];
    const float* w1b = (const float*)d_in[4];  const float* b1b = (const float*)d_in[5];
    const float* w2a = (const float*)d_in[6];  const float* b2a = (const float*)d_in[7];
    const float* w2b = (const float*)d_in[8];  const float* b2b = (const float*)d_in[9];
    const float* w3a = (const float*)d_in[10]; const float* b3a = (const float*)d_in[11];
    const float* w3b = (const float*)d_in[12]; const float* b3b = (const float*)d_in[13];
    const float* wf1 = (const float*)d_in[14]; const float* bf1 = (const float*)d_in[15];
    const float* wf2 = (const float*)d_in[16]; const float* bf2 = (const float*)d_in[17];
    const float* wf3 = (const float*)d_in[18]; const float* bf3 = (const float*)d_in[19];

    char* ws = (char*)d_ws;
    u16* t1uv = (u16*)(ws + 0);
    u16* t2uv = (u16*)(ws + 16384);
    u16* t3uv = (u16*)(ws + 49152);
    u16* t1b  = (u16*)(ws + 180224);
    u16* t2b  = (u16*)(ws + 196608);
    u16* t3b  = (u16*)(ws + 229376);
    u16* tf1  = (u16*)(ws + 491520);
    u16* tf2  = (u16*)(ws + 1933312);
    u16* tf3  = (u16*)(ws + 2457600);
    int*   idxb = (int*)(ws + 2473984);
    float* x1 = (float*)(ws + 4571136);
    float* x2 = (float*)(ws + 8765440);
    float* uvs = (float*)(ws + 17154048);
    u16*   x3 = (u16*)(ws + 33931264);
    u16*   h1 = (u16*)uvs;                // overlays uv scratch after edge3
    u16*   h2 = (u16*)(ws + 4571136);     // overlays x1/x2 after head1

    prep_weights<<<2416, 256, 0, stream>>>(w1a, w1b, w2a, w2b, w3a, w3b, wf1, wf2, wf3,
                                           t1uv, t2uv, t3uv, t1b, t2b, t3b, tf1, tf2, tf3);
    knn_kernel<<<4096, 256, 0, stream>>>(pos, idxb);
    uv_gemm<  3, 32, 128><<<512, 256, 0, stream>>>(x,  t1uv, b1a, uvs);
    edge_pool< 64,  64, false, 1><<<8192, 256, 0, stream>>>(uvs, idxb, t1b, b1b, x1);
    uv_gemm< 64, 64, 128><<<512, 256, 0, stream>>>(x1, t2uv, b2a, uvs);
    edge_pool< 64, 128, false, 2><<<8192, 256, 0, stream>>>(uvs, idxb, t2b, b2b, x2);
    uv_gemm<128, 128, 256><<<512, 256, 0, stream>>>(x2, t3uv, b3a, uvs);
    edge_pool<128, 512, true, 2><<<8192, 256, 0, stream>>>(uvs, idxb, t3b, b3b, x3);
    head1<<<512, 256, 0, stream>>>(x1, x2, x3, tf1, bf1, h1);
    head_bf<512, 256><<<512, 256, 0, stream>>>(h1, tf2, bf2, h2);
    head_gemm3<<<128, 256, 0, stream>>>(h2, tf3, bf3, (float*)d_out);
}